// Round 2
// baseline (300.854 us; speedup 1.0000x reference)
//
#include <hip/hip_runtime.h>
#include <math.h>

#define NROWS 8192
#define DIMX  1024
#define DKV   128
#define KSPLIT 8
#define KEYS_PER_SPLIT (NROWS / KSPLIT)  // 1024
#define BN 64

typedef __attribute__((ext_vector_type(8))) short bf16x8;
typedef __attribute__((ext_vector_type(4))) float f32x4;

static __device__ __forceinline__ short f2bf(float f) {
    union { float f; unsigned u; } v; v.f = f;
    unsigned r = v.u + 0x7fff + ((v.u >> 16) & 1);  // RNE
    return (short)(r >> 16);
}
static __device__ __forceinline__ float bf2f(short s) {
    union { unsigned u; float f; } v; v.u = ((unsigned)(unsigned short)s) << 16;
    return v.f;
}
static __device__ __forceinline__ unsigned pack2(short lo, short hi) {
    return ((unsigned)(unsigned short)hi << 16) | (unsigned short)lo;
}

// ---------------------------------------------------------------------------
// wconv: Wqk, Wv fp32 -> bf16 (one-time, L2-resident afterwards)
// ---------------------------------------------------------------------------
__global__ __launch_bounds__(256) void wconv_kernel(
    const float* __restrict__ Wqk, const float* __restrict__ Wv,
    short* __restrict__ wqb, short* __restrict__ wvb)
{
    const int t = blockIdx.x * 256 + threadIdx.x;   // 0..65535
    const float* src = (t < 32768) ? Wqk : Wv;
    short* dst = (t < 32768) ? wqb : wvb;
    const int i = (t & 32767) * 4;
    const float4 f = *(const float4*)(src + i);
    uint2 p;
    p.x = pack2(f2bf(f.x), f2bf(f.y));
    p.y = pack2(f2bf(f.z), f2bf(f.w));
    *(uint2*)(dst + i) = p;
}

// ---------------------------------------------------------------------------
// proj: register-direct MFMA GEMM, no LDS.
// grid 512 blocks (16 rows each), 4 waves; wave w handles cols w*32..w*32+31
// for BOTH q and v. A from x (fp32->bf16 in regs), B from bf16 weights (L2).
// ---------------------------------------------------------------------------
__global__ __launch_bounds__(256) void proj_kernel(
    const float* __restrict__ x,
    const short* __restrict__ wqb, const float* __restrict__ bqk,
    const short* __restrict__ wvb, const float* __restrict__ bv,
    short* __restrict__ qkb, short* __restrict__ vtb)
{
    const int lane = threadIdx.x & 63;
    const int wave = threadIdx.x >> 6;
    const int l15 = lane & 15, quad = lane >> 4;
    const int row0 = blockIdx.x * 16;
    const int col0 = wave * 32;

    f32x4 accq[2], accv[2];
    for (int i = 0; i < 2; ++i) { accq[i] = (f32x4)0.0f; accv[i] = (f32x4)0.0f; }

    const float* xrow = x + (size_t)(row0 + l15) * DIMX + quad * 8;
    const short* wq0 = wqb + (size_t)(col0 + l15) * DIMX + quad * 8;
    const short* wv0 = wvb + (size_t)(col0 + l15) * DIMX + quad * 8;

    #pragma unroll 2
    for (int k0 = 0; k0 < DIMX; k0 += 32) {
        const float4 a0 = *(const float4*)(xrow + k0);
        const float4 a1 = *(const float4*)(xrow + k0 + 4);
        bf16x8 af;
        af[0] = f2bf(a0.x); af[1] = f2bf(a0.y); af[2] = f2bf(a0.z); af[3] = f2bf(a0.w);
        af[4] = f2bf(a1.x); af[5] = f2bf(a1.y); af[6] = f2bf(a1.z); af[7] = f2bf(a1.w);
        #pragma unroll
        for (int nt = 0; nt < 2; ++nt) {
            const bf16x8 bq = *(const bf16x8*)(wq0 + (size_t)nt * 16 * DIMX + k0);
            accq[nt] = __builtin_amdgcn_mfma_f32_16x16x32_bf16(af, bq, accq[nt], 0, 0, 0);
            const bf16x8 bw = *(const bf16x8*)(wv0 + (size_t)nt * 16 * DIMX + k0);
            accv[nt] = __builtin_amdgcn_mfma_f32_16x16x32_bf16(af, bw, accv[nt], 0, 0, 0);
        }
    }
    // epilogue: C layout col=lane&15, row=quad*4+reg
    const int rw = row0 + quad * 4;
    #pragma unroll
    for (int nt = 0; nt < 2; ++nt) {
        const int col = col0 + nt * 16 + l15;
        const float bq = bqk[col], b2 = bv[col];
        for (int r = 0; r < 4; ++r)
            qkb[(size_t)(rw + r) * DKV + col] = f2bf(accq[nt][r] + bq);
        uint2 pv;
        pv.x = pack2(f2bf(accv[nt][0] + b2), f2bf(accv[nt][1] + b2));
        pv.y = pack2(f2bf(accv[nt][2] + b2), f2bf(accv[nt][3] + b2));
        *(uint2*)(vtb + (size_t)col * NROWS + rw) = pv;
    }
}

// ---------------------------------------------------------------------------
// flash: 64 Q rows x 1024 keys per block; 4 waves x 16 rows; register
// prefetch of next K/V tile; l via all-ones MFMA; conditional rescale.
// grid (128, KSPLIT).
// ---------------------------------------------------------------------------
__global__ __launch_bounds__(256, 3) void flash_kernel(
    const short* __restrict__ qkb, const short* __restrict__ vtb,
    short* __restrict__ opart, float* __restrict__ mpart, float* __restrict__ lpart)
{
    __shared__ __align__(16) short kt[64 * 136];      // 64 keys x 128 d (+8 pad)
    __shared__ __align__(16) short vt[128 * 72];      // 128 d x 64 keys (+8 pad)
    __shared__ __align__(16) short pb[4 * 16 * 72];   // per-wave P

    const int tid  = threadIdx.x;
    const int lane = tid & 63;
    const int wave = tid >> 6;
    const int l15  = lane & 15;
    const int quad = lane >> 4;
    const int rbase = blockIdx.x * 64 + wave * 16;
    const int ks = blockIdx.y;

    bf16x8 qf[4];
    {
        const short* qrow = qkb + (size_t)(rbase + l15) * DKV;
        #pragma unroll
        for (int k = 0; k < 4; ++k)
            qf[k] = *(const bf16x8*)(qrow + k * 32 + quad * 8);
    }
    bf16x8 ones;
    #pragma unroll
    for (int i = 0; i < 8; ++i) ones[i] = (short)0x3F80;   // bf16 1.0

    f32x4 oacc[8];
    #pragma unroll
    for (int i = 0; i < 8; ++i) oacc[i] = (f32x4)0.0f;
    f32x4 lacc = (f32x4)0.0f;
    float m[4] = {-INFINITY, -INFINITY, -INFINITY, -INFINITY};

    const int jb = ks * KEYS_PER_SPLIT, je = jb + KEYS_PER_SPLIT;

    uint4 kreg[4], vreg[4];
    auto load_tile = [&](int j0) {
        #pragma unroll
        for (int i = 0; i < 4; ++i)
            kreg[i] = *(const uint4*)(qkb + (size_t)(j0 + (tid >> 4) + i * 16) * DKV + (tid & 15) * 8);
        #pragma unroll
        for (int i = 0; i < 4; ++i)
            vreg[i] = *(const uint4*)(vtb + (size_t)((tid >> 3) + i * 32) * NROWS + j0 + (tid & 7) * 8);
    };
    auto store_tile = [&]() {
        #pragma unroll
        for (int i = 0; i < 4; ++i)
            *(uint4*)&kt[((tid >> 4) + i * 16) * 136 + (tid & 15) * 8] = kreg[i];
        #pragma unroll
        for (int i = 0; i < 4; ++i)
            *(uint4*)&vt[((tid >> 3) + i * 32) * 72 + (tid & 7) * 8] = vreg[i];
    };

    load_tile(jb);
    store_tile();
    __syncthreads();

    for (int j0 = jb; j0 < je; j0 += BN) {
        const bool more = (j0 + BN) < je;
        if (more) load_tile(j0 + BN);      // in flight during compute

        // S = Q K^T
        f32x4 s[4];
        #pragma unroll
        for (int nt = 0; nt < 4; ++nt) {
            f32x4 acc = (f32x4)0.0f;
            #pragma unroll
            for (int k = 0; k < 4; ++k) {
                const bf16x8 b = *(const bf16x8*)&kt[(nt * 16 + l15) * 136 + k * 32 + quad * 8];
                acc = __builtin_amdgcn_mfma_f32_16x16x32_bf16(qf[k], b, acc, 0, 0, 0);
            }
            s[nt] = acc;
        }

        // row max (16-lane groups)
        float mx[4];
        #pragma unroll
        for (int r = 0; r < 4; ++r) {
            float v = fmaxf(fmaxf(s[0][r], s[1][r]), fmaxf(s[2][r], s[3][r]));
            for (int off = 1; off < 16; off <<= 1)
                v = fmaxf(v, __shfl_xor(v, off));
            mx[r] = v;
        }
        const bool chg = (mx[0] > m[0]) | (mx[1] > m[1]) | (mx[2] > m[2]) | (mx[3] > m[3]);
        if (__ballot(chg)) {               // wave-uniform branch
            float alpha[4];
            #pragma unroll
            for (int r = 0; r < 4; ++r) {
                const float mn = fmaxf(m[r], mx[r]);
                alpha[r] = __expf(m[r] - mn);
                m[r] = mn;
            }
            #pragma unroll
            for (int nt = 0; nt < 8; ++nt)
                for (int r = 0; r < 4; ++r)
                    oacc[nt][r] *= alpha[r];
            #pragma unroll
            for (int r = 0; r < 4; ++r) lacc[r] *= alpha[r];
        }

        // P -> LDS (wave-private, no block barrier needed)
        short* pw = &pb[wave * 16 * 72];
        #pragma unroll
        for (int nt = 0; nt < 4; ++nt)
            #pragma unroll
            for (int r = 0; r < 4; ++r)
                pw[(quad * 4 + r) * 72 + nt * 16 + l15] = f2bf(__expf(s[nt][r] - m[r]));

        // O += P V ; l += P . ones
        #pragma unroll
        for (int k = 0; k < 2; ++k) {
            const bf16x8 a = *(const bf16x8*)&pw[l15 * 72 + k * 32 + quad * 8];
            lacc = __builtin_amdgcn_mfma_f32_16x16x32_bf16(a, ones, lacc, 0, 0, 0);
            #pragma unroll
            for (int nt = 0; nt < 8; ++nt) {
                const bf16x8 b = *(const bf16x8*)&vt[(nt * 16 + l15) * 72 + k * 32 + quad * 8];
                oacc[nt] = __builtin_amdgcn_mfma_f32_16x16x32_bf16(a, b, oacc[nt], 0, 0, 0);
            }
        }

        __syncthreads();                    // all waves done reading kt/vt
        if (more) { store_tile(); __syncthreads(); }
    }

    // store partials (bf16 O, fp32 m/l)
    const int rw = rbase + quad * 4;
    #pragma unroll
    for (int nt = 0; nt < 8; ++nt) {
        const int col = nt * 16 + l15;
        for (int r = 0; r < 4; ++r)
            opart[((size_t)ks * NROWS + rw + r) * DKV + col] = f2bf(oacc[nt][r]);
    }
    if (l15 == 0)
        for (int r = 0; r < 4; ++r) {
            mpart[ks * NROWS + rw + r] = m[r];
            lpart[ks * NROWS + rw + r] = lacc[r];
        }
}

// ---------------------------------------------------------------------------
// combine: merge KSPLIT partials -> out (fp32)
// ---------------------------------------------------------------------------
__global__ __launch_bounds__(256) void combine_kernel(
    const short* __restrict__ opart, const float* __restrict__ mpart,
    const float* __restrict__ lpart, float* __restrict__ out)
{
    const int idx = blockIdx.x * 256 + threadIdx.x;
    const int row = idx >> 7;
    float M = -INFINITY;
    #pragma unroll
    for (int s = 0; s < KSPLIT; ++s) M = fmaxf(M, mpart[s * NROWS + row]);
    float L = 0.f, acc = 0.f;
    #pragma unroll
    for (int s = 0; s < KSPLIT; ++s) {
        const float w = __expf(mpart[s * NROWS + row] - M);
        L += w * lpart[s * NROWS + row];
        acc += w * bf2f(opart[(size_t)s * NROWS * DKV + idx]);
    }
    out[idx] = acc / L;
}

// ---------------------------------------------------------------------------
extern "C" void kernel_launch(void* const* d_in, const int* in_sizes, int n_in,
                              void* d_out, int out_size, void* d_ws, size_t ws_size,
                              hipStream_t stream) {
    const float* x   = (const float*)d_in[0];
    const float* Wqk = (const float*)d_in[1];
    const float* bqk = (const float*)d_in[2];
    const float* Wv  = (const float*)d_in[3];
    const float* bv  = (const float*)d_in[4];
    float* out = (float*)d_out;

    char* ws = (char*)d_ws;
    short* qkb  = (short*)ws;                                // 2 MB  bf16 [N][128]
    short* vtb  = (short*)(ws + (2u << 20));                 // 2 MB  bf16 [128][N]
    short* wqb  = (short*)(ws + (4u << 20));                 // 256 KB bf16 [128][1024]
    short* wvb  = (short*)(ws + (4u << 20) + (256u << 10));  // 256 KB
    float* mpart = (float*)(ws + (4u << 20) + (512u << 10)); // 256 KB fp32 [KS][N]
    float* lpart = (float*)(ws + (4u << 20) + (768u << 10)); // 256 KB
    short* opart = (short*)(ws + (5u << 20));                // 16 MB bf16 [KS][N][128]

    wconv_kernel<<<dim3(256), 256, 0, stream>>>(Wqk, Wv, wqb, wvb);
    proj_kernel<<<dim3(NROWS / 16), 256, 0, stream>>>(x, wqb, bqk, wvb, bv, qkb, vtb);
    flash_kernel<<<dim3(NROWS / 64, KSPLIT), 256, 0, stream>>>(qkb, vtb, opart, mpart, lpart);
    combine_kernel<<<dim3(NROWS * DKV / 256), 256, 0, stream>>>(opart, mpart, lpart, out);
}

// Round 3
// 223.074 us; speedup vs baseline: 1.3487x; 1.3487x over previous
//
#include <hip/hip_runtime.h>
#include <math.h>

#define NROWS 8192
#define DIMX  1024
#define DKV   128
#define KSPLIT 8
#define KEYS_PER_SPLIT (NROWS / KSPLIT)  // 1024
#define BN 64
#define NX (NROWS * DIMX)                // 8388608
#define NW (DKV * DIMX)                  // 131072

typedef __attribute__((ext_vector_type(8))) short bf16x8;
typedef __attribute__((ext_vector_type(4))) float f32x4;

static __device__ __forceinline__ short f2bf(float f) {
    union { float f; unsigned u; } v; v.f = f;
    unsigned r = v.u + 0x7fff + ((v.u >> 16) & 1);  // RNE
    return (short)(r >> 16);
}
static __device__ __forceinline__ unsigned pack2(short lo, short hi) {
    return ((unsigned)(unsigned short)hi << 16) | (unsigned short)lo;
}

// ---------------------------------------------------------------------------
// conv: x, Wqk, Wv fp32 -> bf16 (memory-bound, packed 16B stores)
// grid 4224 blocks x 256 threads, 8 elems/thread
// ---------------------------------------------------------------------------
__global__ __launch_bounds__(256) void conv_kernel(
    const float* __restrict__ x, const float* __restrict__ Wqk,
    const float* __restrict__ Wv,
    short* __restrict__ xb, short* __restrict__ wqb, short* __restrict__ wvb)
{
    const size_t t = (size_t)blockIdx.x * 256 + threadIdx.x;
    const size_t base = t * 8;
    const float* src; short* dst; size_t off;
    if (base < (size_t)NX)           { src = x;   dst = xb;  off = base; }
    else if (base < (size_t)NX + NW) { src = Wqk; dst = wqb; off = base - NX; }
    else                             { src = Wv;  dst = wvb; off = base - NX - NW; }
    const float4 f0 = *(const float4*)(src + off);
    const float4 f1 = *(const float4*)(src + off + 4);
    uint4 p;
    p.x = pack2(f2bf(f0.x), f2bf(f0.y));
    p.y = pack2(f2bf(f0.z), f2bf(f0.w));
    p.z = pack2(f2bf(f1.x), f2bf(f1.y));
    p.w = pack2(f2bf(f1.z), f2bf(f1.w));
    *(uint4*)(dst + off) = p;
}

// ---------------------------------------------------------------------------
// proj: pure-bf16 LDS-staged MFMA GEMM.  grid (128 rowblocks, 2 halves),
// 256 threads.  Block = 64 rows x 128 cols, BK=64, register prefetch.
// half 0 -> qkb row-major; half 1 -> vtb transposed.  Coalesced epilogues.
// ---------------------------------------------------------------------------
__global__ __launch_bounds__(256) void proj_kernel(
    const short* __restrict__ xb,
    const short* __restrict__ wqb, const float* __restrict__ bqk,
    const short* __restrict__ wvb, const float* __restrict__ bv,
    short* __restrict__ qkb, short* __restrict__ vtb)
{
    __shared__ __align__(16) short as[64 * 72];    // 64 rows x 64 k (+8 pad)
    __shared__ __align__(16) short bs[128 * 72];   // 128 cols x 64 k (+8 pad)

    const int tid = threadIdx.x;
    const int lane = tid & 63, wave = tid >> 6;
    const int l15 = lane & 15, quad = lane >> 4;
    const int r0 = blockIdx.x * 64;
    const int half = blockIdx.y;
    const short* W = half ? wvb : wqb;
    const float* bias = half ? bv : bqk;

    f32x4 acc[8];
    #pragma unroll
    for (int i = 0; i < 8; ++i) acc[i] = (f32x4)0.0f;

    const int srow = tid >> 3, ssl = tid & 7;   // 32 rows per inst round

    uint4 areg[2], breg[4];
    auto load_tiles = [&](int kc) {
        #pragma unroll
        for (int i = 0; i < 2; ++i)
            areg[i] = *(const uint4*)(xb + (size_t)(r0 + srow + i * 32) * DIMX + kc + ssl * 8);
        #pragma unroll
        for (int i = 0; i < 4; ++i)
            breg[i] = *(const uint4*)(W + (size_t)(srow + i * 32) * DIMX + kc + ssl * 8);
    };
    auto store_tiles = [&]() {
        #pragma unroll
        for (int i = 0; i < 2; ++i)
            *(uint4*)&as[(srow + i * 32) * 72 + ssl * 8] = areg[i];
        #pragma unroll
        for (int i = 0; i < 4; ++i)
            *(uint4*)&bs[(srow + i * 32) * 72 + ssl * 8] = breg[i];
    };

    load_tiles(0);
    store_tiles();
    __syncthreads();

    for (int kc = 0; kc < DIMX; kc += 64) {
        const bool more = (kc + 64) < DIMX;
        if (more) load_tiles(kc + 64);
        #pragma unroll
        for (int ks = 0; ks < 2; ++ks) {
            const bf16x8 a = *(const bf16x8*)&as[(wave * 16 + l15) * 72 + ks * 32 + quad * 8];
            #pragma unroll
            for (int nt = 0; nt < 8; ++nt) {
                const bf16x8 b = *(const bf16x8*)&bs[(nt * 16 + l15) * 72 + ks * 32 + quad * 8];
                acc[nt] = __builtin_amdgcn_mfma_f32_16x16x32_bf16(a, b, acc[nt], 0, 0, 0);
            }
        }
        __syncthreads();
        if (more) { store_tiles(); __syncthreads(); }
    }

    // epilogue via LDS transpose (reuse bs), fully coalesced 16B stores
    short* ot = bs;
    if (half == 0) {
        // layout [64 rows][136]
        #pragma unroll
        for (int nt = 0; nt < 8; ++nt) {
            const float b = bias[nt * 16 + l15];
            #pragma unroll
            for (int r = 0; r < 4; ++r)
                ot[(wave * 16 + quad * 4 + r) * 136 + nt * 16 + l15] = f2bf(acc[nt][r] + b);
        }
        __syncthreads();
        #pragma unroll
        for (int i = 0; i < 4; ++i) {
            const int flat = i * 256 + tid;
            const int row = flat >> 4, sl = flat & 15;
            *(uint4*)(qkb + (size_t)(r0 + row) * DKV + sl * 8) = *(const uint4*)&ot[row * 136 + sl * 8];
        }
    } else {
        // layout [128 cols][72] (transposed)
        #pragma unroll
        for (int nt = 0; nt < 8; ++nt) {
            const float b = bias[nt * 16 + l15];
            #pragma unroll
            for (int r = 0; r < 4; ++r)
                ot[(nt * 16 + l15) * 72 + wave * 16 + quad * 4 + r] = f2bf(acc[nt][r] + b);
        }
        __syncthreads();
        #pragma unroll
        for (int i = 0; i < 4; ++i) {
            const int flat = i * 256 + tid;
            const int col = flat >> 3, sl = flat & 7;
            *(uint4*)(vtb + (size_t)col * NROWS + r0 + sl * 8) = *(const uint4*)&ot[col * 72 + sl * 8];
        }
    }
}

// ---------------------------------------------------------------------------
// flash: 128 Q rows x 1024 keys per block; 8 waves x 16 rows; register
// prefetch; l via ones-MFMA; conditional rescale; fp32 full-line O stores.
// grid (64, KSPLIT), 512 threads.
// ---------------------------------------------------------------------------
__global__ __launch_bounds__(512, 4) void flash_kernel(
    const short* __restrict__ qkb, const short* __restrict__ vtb,
    float* __restrict__ opart, float* __restrict__ mpart, float* __restrict__ lpart)
{
    __shared__ __align__(16) short kt[64 * 136];      // 64 keys x 128 d (+8)
    __shared__ __align__(16) short vt[128 * 72];      // 128 d x 64 keys (+8)
    __shared__ __align__(16) short pb[8 * 16 * 76];   // per-wave P, stride 76

    const int tid  = threadIdx.x;
    const int lane = tid & 63;
    const int wave = tid >> 6;
    const int l15  = lane & 15;
    const int quad = lane >> 4;
    const int rbase = blockIdx.x * 128 + wave * 16;
    const int ks = blockIdx.y;

    bf16x8 qf[4];
    {
        const short* qrow = qkb + (size_t)(rbase + l15) * DKV;
        #pragma unroll
        for (int k = 0; k < 4; ++k)
            qf[k] = *(const bf16x8*)(qrow + k * 32 + quad * 8);
    }
    bf16x8 ones;
    #pragma unroll
    for (int i = 0; i < 8; ++i) ones[i] = (short)0x3F80;

    f32x4 oacc[8];
    #pragma unroll
    for (int i = 0; i < 8; ++i) oacc[i] = (f32x4)0.0f;
    f32x4 lacc = (f32x4)0.0f;
    float m[4] = {-INFINITY, -INFINITY, -INFINITY, -INFINITY};

    const int jb = ks * KEYS_PER_SPLIT, je = jb + KEYS_PER_SPLIT;

    const int krow = tid >> 4, kch = tid & 15;   // 32 key-rows / inst round
    const int vrow = tid >> 3, vch = tid & 7;    // 64 d-rows / inst round
    uint4 kreg[2], vreg[2];
    auto load_tile = [&](int j0) {
        #pragma unroll
        for (int i = 0; i < 2; ++i)
            kreg[i] = *(const uint4*)(qkb + (size_t)(j0 + krow + i * 32) * DKV + kch * 8);
        #pragma unroll
        for (int i = 0; i < 2; ++i)
            vreg[i] = *(const uint4*)(vtb + (size_t)(vrow + i * 64) * NROWS + j0 + vch * 8);
    };
    auto store_tile = [&]() {
        #pragma unroll
        for (int i = 0; i < 2; ++i)
            *(uint4*)&kt[(krow + i * 32) * 136 + kch * 8] = kreg[i];
        #pragma unroll
        for (int i = 0; i < 2; ++i)
            *(uint4*)&vt[(vrow + i * 64) * 72 + vch * 8] = vreg[i];
    };

    load_tile(jb);
    store_tile();
    __syncthreads();

    for (int j0 = jb; j0 < je; j0 += BN) {
        const bool more = (j0 + BN) < je;
        if (more) load_tile(j0 + BN);      // in flight during compute

        // S = Q K^T
        f32x4 s[4];
        #pragma unroll
        for (int nt = 0; nt < 4; ++nt) {
            f32x4 acc = (f32x4)0.0f;
            #pragma unroll
            for (int k = 0; k < 4; ++k) {
                const bf16x8 b = *(const bf16x8*)&kt[(nt * 16 + l15) * 136 + k * 32 + quad * 8];
                acc = __builtin_amdgcn_mfma_f32_16x16x32_bf16(qf[k], b, acc, 0, 0, 0);
            }
            s[nt] = acc;
        }

        // row max (16-lane groups)
        float mx[4];
        #pragma unroll
        for (int r = 0; r < 4; ++r) {
            float v = fmaxf(fmaxf(s[0][r], s[1][r]), fmaxf(s[2][r], s[3][r]));
            for (int off = 1; off < 16; off <<= 1)
                v = fmaxf(v, __shfl_xor(v, off));
            mx[r] = v;
        }
        const bool chg = (mx[0] > m[0]) | (mx[1] > m[1]) | (mx[2] > m[2]) | (mx[3] > m[3]);
        if (__ballot(chg)) {               // wave-uniform
            float alpha[4];
            #pragma unroll
            for (int r = 0; r < 4; ++r) {
                const float mn = fmaxf(m[r], mx[r]);
                alpha[r] = __expf(m[r] - mn);
                m[r] = mn;
            }
            #pragma unroll
            for (int nt = 0; nt < 8; ++nt)
                for (int r = 0; r < 4; ++r)
                    oacc[nt][r] *= alpha[r];
            #pragma unroll
            for (int r = 0; r < 4; ++r) lacc[r] *= alpha[r];
        }

        // P -> LDS (wave-private)
        short* pw = &pb[wave * 16 * 76];
        #pragma unroll
        for (int nt = 0; nt < 4; ++nt)
            #pragma unroll
            for (int r = 0; r < 4; ++r)
                pw[(quad * 4 + r) * 76 + nt * 16 + l15] = f2bf(__expf(s[nt][r] - m[r]));

        // O += P V ; l += P . 1
        #pragma unroll
        for (int k = 0; k < 2; ++k) {
            const bf16x8 a = *(const bf16x8*)&pw[l15 * 76 + k * 32 + quad * 8];
            lacc = __builtin_amdgcn_mfma_f32_16x16x32_bf16(a, ones, lacc, 0, 0, 0);
            #pragma unroll
            for (int nt = 0; nt < 8; ++nt) {
                const bf16x8 b = *(const bf16x8*)&vt[(nt * 16 + l15) * 72 + k * 32 + quad * 8];
                oacc[nt] = __builtin_amdgcn_mfma_f32_16x16x32_bf16(a, b, oacc[nt], 0, 0, 0);
            }
        }

        __syncthreads();
        if (more) { store_tile(); __syncthreads(); }
    }

    // store partials: fp32, 16 lanes x 4B = full 64B lines
    const int rw = rbase + quad * 4;
    #pragma unroll
    for (int nt = 0; nt < 8; ++nt) {
        const int col = nt * 16 + l15;
        #pragma unroll
        for (int r = 0; r < 4; ++r)
            opart[((size_t)ks * NROWS + rw + r) * DKV + col] = oacc[nt][r];
    }
    if (l15 == 0)
        #pragma unroll
        for (int r = 0; r < 4; ++r) {
            mpart[ks * NROWS + rw + r] = m[r];
            lpart[ks * NROWS + rw + r] = lacc[r];
        }
}

// ---------------------------------------------------------------------------
// combine: merge KSPLIT partials -> out (fp32)
// ---------------------------------------------------------------------------
__global__ __launch_bounds__(256) void combine_kernel(
    const float* __restrict__ opart, const float* __restrict__ mpart,
    const float* __restrict__ lpart, float* __restrict__ out)
{
    const int idx = blockIdx.x * 256 + threadIdx.x;
    const int row = idx >> 7;
    float M = -INFINITY;
    #pragma unroll
    for (int s = 0; s < KSPLIT; ++s) M = fmaxf(M, mpart[s * NROWS + row]);
    float L = 0.f, acc = 0.f;
    #pragma unroll
    for (int s = 0; s < KSPLIT; ++s) {
        const float w = __expf(mpart[s * NROWS + row] - M);
        L += w * lpart[s * NROWS + row];
        acc += w * opart[(size_t)s * NROWS * DKV + idx];
    }
    out[idx] = acc / L;
}

// ---------------------------------------------------------------------------
extern "C" void kernel_launch(void* const* d_in, const int* in_sizes, int n_in,
                              void* d_out, int out_size, void* d_ws, size_t ws_size,
                              hipStream_t stream) {
    const float* x   = (const float*)d_in[0];
    const float* Wqk = (const float*)d_in[1];
    const float* bqk = (const float*)d_in[2];
    const float* Wv  = (const float*)d_in[3];
    const float* bv  = (const float*)d_in[4];
    float* out = (float*)d_out;

    char* ws = (char*)d_ws;
    short* qkb   = (short*)ws;                                 // 2 MB  bf16 [N][128]
    short* vtb   = (short*)(ws + (2u << 20));                  // 2 MB  bf16 [128][N]
    short* wqb   = (short*)(ws + (4u << 20));                  // 256 KB
    short* wvb   = (short*)(ws + (4u << 20) + (256u << 10));   // 256 KB
    float* mpart = (float*)(ws + (4u << 20) + (512u << 10));   // 256 KB fp32 [KS][N]
    float* lpart = (float*)(ws + (4u << 20) + (768u << 10));   // 256 KB
    short* xb    = (short*)(ws + (5u << 20));                  // 16.8 MB bf16 [N][1024]
    float* opart = (float*)(ws + (22u << 20));                 // 33.6 MB fp32 [KS][N][128]

    conv_kernel<<<dim3((NX + 2 * NW) / 2048), 256, 0, stream>>>(x, Wqk, Wv, xb, wqb, wvb);
    proj_kernel<<<dim3(NROWS / 64, 2), 256, 0, stream>>>(xb, wqb, bqk, wvb, bv, qkb, vtb);
    flash_kernel<<<dim3(NROWS / 128, KSPLIT), 512, 0, stream>>>(qkb, vtb, opart, mpart, lpart);
    combine_kernel<<<dim3(NROWS * DKV / 256), 256, 0, stream>>>(opart, mpart, lpart, out);
}